// Round 10
// baseline (57538.995 us; speedup 1.0000x reference)
//
#include <hip/hip_runtime.h>
#include <hip/hip_bf16.h>

// Problem constants (B=256, T=512, H=512, IN=1, future=64)
#define TT  512
#define BB  256
#define HH  512
#define FUT 64
#define NBLK 64            // 2 roles x 16 unit-groups x 2 batch-groups

// Output dtype FP32. Beacons: float 2^(20+code)*(1+m/128):
//  0: n_in!=22  1: in_sizes mismatch @m  2: ws too small  6: out_size wrong
// r22 = r21 with the streamed matrix sourced from the INPUT buffer.
// r21 postmortem: FETCH_SIZE 1.1GB = full Whh1 re-fetched from fabric every
// step -> WORKSPACE IS UNCACHED (fine-grained). Explains r16 (cached-h
// never cached), r20 (probe trivially passed), and the 2.06 TB/s "law"
// (uncached-fabric ceiling). Input buffers (d_in) are coarse-grained ->
// cacheable: stream role1's Whh1/pWhh1 from d_in[7]/d_in[17] (L2-resident,
// 4 blocks/XCD x <=512KB slice each), cvt f32->bf16 in regs via
// v_cvt_pk_bf16_f32 when dt==1.
// Rest = r21/r18: U=32 role blocks, barrier-free per-step counters,
// h0 ring-4 / h1 ring-2, sc0sc1 h exchange (12 MB/step -> ~5.8us floor),
// distributed head partials, bounded spins (hang -> passed:false).

struct Hdr { int dtflag; };

typedef __attribute__((ext_vector_type(8))) short short8;
typedef __attribute__((ext_vector_type(4))) float floatx4;

#define OFF_FLG   4096
#define OFF_W     20480
#define WSZ       ((size_t)2048*512*2)          // 2MB bf16 matrix
#define OFF_H0    (OFF_W + 6*WSZ)               // h0 ring: 4 x 256KB
#define HSZ       ((size_t)BB*HH*2)             // 256KB bf16 state
#define OFF_H1    (OFF_H0 + 4*HSZ)              // h1 ring: 2 x 256KB
#define OFF_OA    (OFF_H1 + 2*HSZ)              // o accumulators
#define OASZ      ((size_t)FUT*BB*4)            // 64KB fp32
#define NEED_WS   (OFF_OA + OASZ)               // ~14.2MB

#define SPIN_CAP  (1L << 22)

__device__ __forceinline__ float bf2f(short s) {
  unsigned u = ((unsigned)(unsigned short)s) << 16;
  return __builtin_bit_cast(float, u);
}
__device__ __forceinline__ short f2bf(float f) {
  unsigned u = __builtin_bit_cast(unsigned, f);
  u = u + 0x7FFFu + ((u >> 16) & 1u);
  return (short)(u >> 16);
}
__device__ __forceinline__ float ldf(const void* p, long i, int dt) {
  return dt ? ((const float*)p)[i] : bf2f(((const short*)p)[i]);
}
// 16B coherence-point load/store: dwordx4 with sc0 sc1 (bypass caches,
// IC is the coherence point). Result not ready until manual WAITV.
__device__ __forceinline__ short8 cohld16(const short* p) {
  short8 v;
  asm volatile("global_load_dwordx4 %0, %1, off sc0 sc1"
               : "=v"(v) : "v"(p));
  return v;
}
__device__ __forceinline__ void cohst16(short* p, short8 v) {
  asm volatile("global_store_dwordx4 %0, %1, off sc0 sc1"
               :: "v"(p), "v"(v) : "memory");
}
// streamed-weight fragment loads from INPUT buffer (plain cached loads,
// compiler-scheduled). f32 path converts 8 floats -> 8 bf16 via cvt_pk.
__device__ __forceinline__ short8 ldwf_bf(const short* p) {
  return *(const short8*)p;
}
__device__ __forceinline__ short8 ldwf_f32(const float* p) {
  const float4 lo = *(const float4*)p;
  const float4 hi = *(const float4*)(p + 4);
  union { short8 s; unsigned u[4]; } r;
  asm("v_cvt_pk_bf16_f32 %0, %1, %2" : "=v"(r.u[0]) : "v"(lo.x), "v"(lo.y));
  asm("v_cvt_pk_bf16_f32 %0, %1, %2" : "=v"(r.u[1]) : "v"(lo.z), "v"(lo.w));
  asm("v_cvt_pk_bf16_f32 %0, %1, %2" : "=v"(r.u[2]) : "v"(hi.x), "v"(hi.y));
  asm("v_cvt_pk_bf16_f32 %0, %1, %2" : "=v"(r.u[3]) : "v"(hi.z), "v"(hi.w));
  return r.s;
}
// counted wait + hard scheduling fence (rule #18: keep MFMA below the wait)
#define WAITV(N) do { asm volatile("s_waitcnt vmcnt(" #N ")" ::: "memory"); \
                      __builtin_amdgcn_sched_barrier(0); } while (0)

__global__ void beacon_kernel(float* dout, float v) {
  if (threadIdx.x == 0) dout[0] = v;
}

__global__ __launch_bounds__(256) void probe1_kernel(const void* w, Hdr* hdr) {
  const int tid = threadIdx.x;
  const short* s = (const short*)w;
  float mx = 0.f;
  #pragma unroll
  for (int i = 0; i < 16; ++i) {
    float v = fabsf(bf2f(s[tid * 16 + i]));
    if (!(v == v)) v = 1e30f;
    mx = fmaxf(mx, v);
  }
  #pragma unroll
  for (int off = 32; off > 0; off >>= 1) mx = fmaxf(mx, __shfl_down(mx, off));
  __shared__ float wmax[4];
  if ((tid & 63) == 0) wmax[tid >> 6] = mx;
  __syncthreads();
  if (tid == 0) {
    float m = fmaxf(fmaxf(wmax[0], wmax[1]), fmaxf(wmax[2], wmax[3]));
    hdr->dtflag = (m > 1000.f) ? 1 : 0;
  }
}

__global__ __launch_bounds__(256) void cvt_kernel(const void* src, short* dst,
                                                  const Hdr* hdr) {
  const int dt = hdr->dtflag;
  const long i = ((long)blockIdx.x * 256 + threadIdx.x);
  if (dt) {
    const float4 v = ((const float4*)src)[i];
    short4 o;
    o.x = f2bf(v.x); o.y = f2bf(v.y); o.z = f2bf(v.z); o.w = f2bf(v.w);
    ((short4*)dst)[i] = o;
  } else {
    ((short4*)dst)[i] = ((const short4*)src)[i];
  }
}

// Persistent 2-layer LSTM, layer-split roles (U=32), counter pipeline.
__global__ __launch_bounds__(512, 1) void lstm_persist(
    const void* __restrict__ x,
    const void* __restrict__ w_ih0, const void* __restrict__ b_ih0,
    const void* __restrict__ b_hh0, const void* __restrict__ b_ih1,
    const void* __restrict__ b_hh1, const void* __restrict__ fc_w,
    const void* __restrict__ fc_b,  const void* __restrict__ pw_ih0,
    const void* __restrict__ pb_ih0, const void* __restrict__ pb_hh0,
    const void* __restrict__ pb_ih1, const void* __restrict__ pb_hh1,
    const void* __restrict__ pfc_w, const void* __restrict__ pfc_b,
    const short* __restrict__ Whh0, const short* __restrict__ Wih1,
    const short* __restrict__ pWhh0, const short* __restrict__ pWih1,
    const void* __restrict__ Whh1in, const void* __restrict__ pWhh1in,
    short* H0R, short* H1R, float* oA, int* flg,
    const Hdr* __restrict__ hdr, float* __restrict__ dout)
{
  const int dt  = hdr->dtflag;
  const int tid = threadIdx.x;
  const int role = blockIdx.x & 1;         // 0 = layer0, 1 = layer1
  const int bg   = (blockIdx.x >> 1) & 1;  // 0..1
  const int ug   = blockIdx.x >> 2;        // 0..15
  const int U0   = ug * 32;
  const int B0   = bg * 128;

  // per-bg counter bank (batch-groups are fully independent)
  int* F     = flg + bg * 2048;
  int* pub0  = F;          // [0..575]
  int* pub1  = F + 576;    // [0..575]
  int* cons1 = F + 1152;   // [0..575]
  int* opub  = F + 1728;   // [0..63]

  // 128KB: ONE matrix. [kseg(64)][row(128)][8]; row = unit_local*4 + gate.
  // role0: Whh0/pWhh0. role1: Wih1/pWih1 (Whh1/pWhh1 streamed from input).
  __shared__ __align__(16) short Wl[64][128][8];
  __shared__ __align__(16) short hbuf[128][32];  // 8KB h repack
  __shared__ float bs[128];                      // bias, idx = u*4+gate
  __shared__ float wih[128];                     // w_ih col (L0 only)

  const int lane = tid & 63;
  const int wv   = tid >> 6;           // wave 0..7: 16-batch slice each
  const int ln   = lane & 15;          // batch-in-tile AND W-row-in-tile
  const int q    = lane >> 4;          // k-slice / unit-in-quad
  const int bl   = wv*16 + ln;         // batch-in-block 0..127
  const long abase  = (long)(B0 + bl) * 512 + q*8;
  // streamed-W per-lane ELEMENT base: global row (ln&3)*512 + U0 + (ln>>2);
  // +mt*2048 walks m-tiles (4 rows), +kb*32 walks K.
  const long wsbase = ((long)(ln & 3)*512 + U0 + (ln >> 2))*512 + q*8;

  // per-lane cell state: unit = U0 + mt*4 + q, batch = B0 + bl
  float cst[8] = {0.f,0.f,0.f,0.f,0.f,0.f,0.f,0.f};
  float fwk[8] = {0.f,0.f,0.f,0.f,0.f,0.f,0.f,0.f};

// ring slot bases (131072 shorts = one 256KB h state)
#define H0S(G) (H0R + (size_t)((G) & 3) * 131072)
#define H1S(G) (H1R + (size_t)((G) & 1) * 131072)

// bounded spin (anti-hang): protocol failure -> garbage, not dead container
#define SPIN(COND)                                                           \
  { long guard_ = 0;                                                         \
    while (COND) {                                                           \
      __builtin_amdgcn_s_sleep(1);                                           \
      if (++guard_ > SPIN_CAP) break;                                        \
    } }
#define POLL(P, T)                                                           \
  SPIN(__hip_atomic_load((P), __ATOMIC_RELAXED,                              \
                         __HIP_MEMORY_SCOPE_SYSTEM) < (T))
#define FADD(P)                                                              \
  __hip_atomic_fetch_add((P), 1, __ATOMIC_RELAXED,                           \
                         __HIP_MEMORY_SCOPE_SYSTEM)

// stage one 128KB matrix slice (32 units), global-coalesced (one-time)
#define STAGE32(WG)                                                          \
  for (int i = tid; i < 8192; i += 512) {                                    \
    const int ks_ = i & 63, r_ = i >> 6;                                     \
    const long gr = (long)((r_ & 3)*512 + U0 + (r_ >> 2))*512 + ks_*8;       \
    *(short8*)&Wl[ks_][r_][0] = *(const short8*)((WG) + gr);                 \
  }

#define BIAS32(B1, B2, WIHP)                                                 \
  if (tid < 128) {                                                           \
    const long j = (long)(tid & 3)*512 + U0 + (tid >> 2);                    \
    bs[tid] = ldf((B1), j, dt) + ldf((B2), j, dt);                           \
    wih[tid] = (WIHP) ? ldf((const void*)(WIHP), j, dt) : 0.f;               \
  }

#define FWLOAD(FWP)                                                          \
  { _Pragma("unroll")                                                        \
    for (int mt = 0; mt < 8; ++mt)                                           \
      fwk[mt] = ldf((FWP), U0 + mt*4 + q, dt); }

#define ZACC(A)                                                              \
  _Pragma("unroll") for (int m_ = 0; m_ < 8; ++m_)                           \
    A[m_] = (floatx4){0.f, 0.f, 0.f, 0.f};

// role0 pass: h0 x Wl(LDS); 16 kb, 2 groups of 8, 2-deep counted pipeline
#define GSEG0(AP, ACC)                                                       \
  { const short* ap_ = (AP) + abase;                                         \
    short8 abuf[2][8];                                                       \
    _Pragma("unroll")                                                        \
    for (int i = 0; i < 8; ++i) abuf[0][i] = cohld16(ap_ + i*32);            \
    _Pragma("unroll")                                                        \
    for (int g = 0; g < 2; ++g) {                                            \
      if (g == 0) {                                                          \
        _Pragma("unroll")                                                    \
        for (int i = 0; i < 8; ++i)                                          \
          abuf[1][i] = cohld16(ap_ + (8+i)*32);                              \
        WAITV(8);                                                            \
      } else { WAITV(0); }                                                   \
      _Pragma("unroll")                                                      \
      for (int kk = 0; kk < 8; ++kk) {                                       \
        const int kb = g*8 + kk;                                             \
        _Pragma("unroll")                                                    \
        for (int mt = 0; mt < 8; ++mt) {                                     \
          short8 wf = *(const short8*)&Wl[kb*4 + q][mt*16 + ln][0];          \
          ACC[mt] = __builtin_amdgcn_mfma_f32_16x16x32_bf16(                 \
              wf, abuf[g][kk], ACC[mt], 0, 0, 0);                            \
        }                                                                    \
      }                                                                      \
    } }

// role1 pass: pass1 = h0 x Wl(LDS), h1 prefetched into regs in the same
// counted groups; pass2 = h1 x W(streamed from INPUT, cached,
// compiler-scheduled; dt-hoisted f32->bf16 cvt).
#define GSEG1(AP0, AP1, WSI, ACC)                                            \
  { const short* p0_ = (AP0) + abase;                                        \
    const short* p1_ = (AP1) + abase;                                        \
    short8 abuf[2][4], h1r[16];                                              \
    _Pragma("unroll")                                                        \
    for (int i = 0; i < 4; ++i) {                                            \
      abuf[0][i] = cohld16(p0_ + i*32);                                      \
      h1r[i]     = cohld16(p1_ + i*32);                                      \
    }                                                                        \
    _Pragma("unroll")                                                        \
    for (int g = 0; g < 4; ++g) {                                            \
      if (g < 3) {                                                           \
        _Pragma("unroll")                                                    \
        for (int i = 0; i < 4; ++i) {                                        \
          abuf[(g+1)&1][i] = cohld16(p0_ + ((g+1)*4 + i)*32);                \
          h1r[(g+1)*4 + i] = cohld16(p1_ + ((g+1)*4 + i)*32);                \
        }                                                                    \
        WAITV(8);                                                            \
      } else { WAITV(0); }                                                   \
      _Pragma("unroll")                                                      \
      for (int kk = 0; kk < 4; ++kk) {                                       \
        const int kb = g*4 + kk;                                             \
        _Pragma("unroll")                                                    \
        for (int mt = 0; mt < 8; ++mt) {                                     \
          short8 wf = *(const short8*)&Wl[kb*4 + q][mt*16 + ln][0];          \
          ACC[mt] = __builtin_amdgcn_mfma_f32_16x16x32_bf16(                 \
              wf, abuf[g&1][kk], ACC[mt], 0, 0, 0);                          \
        }                                                                    \
      }                                                                      \
    }                                                                        \
    if (dt) {                                                                \
      const float* wb_ = (const float*)(WSI) + wsbase;                       \
      _Pragma("unroll")                                                      \
      for (int kb = 0; kb < 16; ++kb) {                                      \
        _Pragma("unroll")                                                    \
        for (int mt = 0; mt < 8; ++mt) {                                     \
          short8 wf = ldwf_f32(wb_ + mt*2048 + kb*32);                       \
          ACC[mt] = __builtin_amdgcn_mfma_f32_16x16x32_bf16(                 \
              wf, h1r[kb], ACC[mt], 0, 0, 0);                                \
        }                                                                    \
      }                                                                      \
    } else {                                                                 \
      const short* wb_ = (const short*)(WSI) + wsbase;                       \
      _Pragma("unroll")                                                      \
      for (int kb = 0; kb < 16; ++kb) {                                      \
        _Pragma("unroll")                                                    \
        for (int mt = 0; mt < 8; ++mt) {                                     \
          short8 wf = ldwf_bf(wb_ + mt*2048 + kb*32);                        \
          ACC[mt] = __builtin_amdgcn_mfma_f32_16x16x32_bf16(                 \
              wf, h1r[kb], ACC[mt], 0, 0, 0);                                \
        }                                                                    \
      }                                                                      \
    } }

// in-lane epilogue. MODE 0: sv = x[b][TV]; 1: none; 2: sv = SVO (o value).
// OSLOT != 0: accumulate head partial fc.h, atomicAdd per batch.
// Ends fully drained (per-wave vmcnt0) + block-synced.
#define EPI32(ACC, MODE, TV, SVO, HOUT, OSLOT)                               \
  { float sv = 0.f;                                                          \
    if ((MODE) == 0)      sv = ldf(x, (long)(B0 + bl)*TT + (TV), dt);        \
    else if ((MODE) == 2) sv = (SVO);                                        \
    float po = 0.f;                                                          \
    _Pragma("unroll")                                                        \
    for (int mt = 0; mt < 8; ++mt) {                                         \
      const int u = mt*4 + q;                                                \
      float gi = ACC[mt][0] + bs[u*4+0];                                     \
      float gf = ACC[mt][1] + bs[u*4+1];                                     \
      float gg = ACC[mt][2] + bs[u*4+2];                                     \
      float go = ACC[mt][3] + bs[u*4+3];                                     \
      if ((MODE) != 1) {                                                     \
        gi += sv*wih[u*4+0]; gf += sv*wih[u*4+1];                            \
        gg += sv*wih[u*4+2]; go += sv*wih[u*4+3];                            \
      }                                                                      \
      const float I = 1.f/(1.f+expf(-gi));                                   \
      const float F = 1.f/(1.f+expf(-gf));                                   \
      const float G = tanhf(gg);                                             \
      const float O = 1.f/(1.f+expf(-go));                                   \
      const float cn = F*cst[mt] + I*G;                                      \
      cst[mt] = cn;                                                          \
      const float hv = O * tanhf(cn);                                        \
      hbuf[bl][u] = f2bf(hv);                                                \
      po += fwk[mt] * hv;                                                    \
    }                                                                        \
    if ((OSLOT) != (float*)0) {                                              \
      po += __shfl_xor(po, 16); po += __shfl_xor(po, 32);                    \
      if (lane < 16) atomicAdd((float*)(OSLOT) + bl, po);                    \
    }                                                                        \
    __syncthreads();                                                         \
    { const int b_ = tid >> 2, hf_ = tid & 3;                                \
      short8 hv8 = *(const short8*)&hbuf[b_][hf_*8];                         \
      cohst16((HOUT) + (long)(B0 + b_)*512 + U0 + hf_*8, hv8); }             \
    asm volatile("s_waitcnt vmcnt(0)" ::: "memory");                         \
    __syncthreads(); }

  const float fcb  = ldf(fc_b, 0, dt);
  const float pfcb = ldf(pfc_b, 0, dt);

  if (role == 0) {
    // ======== role0: L0 chain (U=32), Whh0 in LDS, runs ahead ========
    STAGE32(Whh0);
    BIAS32(b_ih0, b_hh0, w_ih0);
    __syncthreads();
    for (int g = 0; g < TT; ++g) {
      if (tid == 0) {
        if (g > 0)  POLL(pub0 + g - 1, 16);     // peers published h0(g-1)
        if (g >= 4) POLL(cons1 + g - 4, 16);    // ring-4 backpressure
      }
      __syncthreads();
      floatx4 a[8]; ZACC(a);
      GSEG0(H0S(g-1), a);
      EPI32(a, 0, g, 0.f, H0S(g), (float*)0);
      if (tid == 0) FADD(pub0 + g);
    }
    // transition: decode weights (block-local)
    STAGE32(pWhh0);
    BIAS32(pb_ih0, pb_hh0, pw_ih0);
    __syncthreads();
    // decode L0: consumes o(s-1) from role1's head partials
    for (int s = 1; s < FUT; ++s) {
      const int g = 511 + s;
      if (tid == 0) {
        POLL(pub0 + g - 1, 16);
        POLL(cons1 + g - 4, 16);
        POLL(opub + s - 1, 16);
      }
      __syncthreads();
      const float ob_ = (s == 1) ? fcb : pfcb;
      const float o_ = __hip_atomic_load(
          oA + (long)(s-1)*BB + B0 + bl,
          __ATOMIC_RELAXED, __HIP_MEMORY_SCOPE_SYSTEM) + ob_;
      if (ug == 0 && lane < 16)
        dout[(long)(B0 + bl)*FUT + (s-1)] = o_;
      floatx4 a[8]; ZACC(a);
      GSEG0(H0S(g-1), a);
      EPI32(a, 2, 0, o_, H0S(g), (float*)0);
      if (tid == 0) FADD(pub0 + g);
    }
    // tail: emit dout col 63
    if (tid == 0) POLL(opub + FUT - 1, 16);
    __syncthreads();
    if (ug == 0 && lane < 16) {
      const float o_ = __hip_atomic_load(
          oA + (long)(FUT-1)*BB + B0 + bl,
          __ATOMIC_RELAXED, __HIP_MEMORY_SCOPE_SYSTEM) + pfcb;
      dout[(long)(B0 + bl)*FUT + (FUT-1)] = o_;
    }
  } else {
    // ==== role1: L1 chain (U=32), Wih1 LDS + Whh1 streamed from input ====
    STAGE32(Wih1);
    BIAS32(b_ih1, b_hh1, (const void*)0);
    FWLOAD(fc_w);
    __syncthreads();
    for (int g = 0; g < TT; ++g) {
      if (tid == 0) {
        POLL(pub0 + g, 16);                     // h0(g) ready
        if (g > 0) POLL(pub1 + g - 1, 16);      // peers' h1(g-1)
      }
      __syncthreads();
      floatx4 a[8]; ZACC(a);
      GSEG1(H0S(g), H1S(g-1), Whh1in, a);
      __syncthreads();                          // all waves done with h0(g)
      if (tid == 0) FADD(cons1 + g);
      float* os_ = (g == TT-1) ? (oA + B0) : (float*)0;  // head @ last step
      EPI32(a, 1, 0, 0.f, H1S(g), os_);
      if (tid == 0) {
        FADD(pub1 + g);
        if (g == TT-1) FADD(opub + 0);
      }
    }
    // transition: decode weights (block-local)
    STAGE32(pWih1);
    BIAS32(pb_ih1, pb_hh1, (const void*)0);
    FWLOAD(pfc_w);
    __syncthreads();
    for (int s = 1; s < FUT; ++s) {
      const int g = 511 + s;
      if (tid == 0) {
        POLL(pub0 + g, 16);
        POLL(pub1 + g - 1, 16);
      }
      __syncthreads();
      floatx4 a[8]; ZACC(a);
      GSEG1(H0S(g), H1S(g-1), pWhh1in, a);
      __syncthreads();
      if (tid == 0) FADD(cons1 + g);
      EPI32(a, 1, 0, 0.f, H1S(g), oA + (long)s*BB + B0);
      if (tid == 0) { FADD(pub1 + g); FADD(opub + s); }
    }
  }
#undef STAGE32
#undef BIAS32
#undef FWLOAD
#undef ZACC
#undef GSEG0
#undef GSEG1
#undef EPI32
#undef SPIN
#undef POLL
#undef FADD
#undef H0S
#undef H1S
}

extern "C" void kernel_launch(void* const* d_in, const int* in_sizes, int n_in,
                              void* d_out, int out_size, void* d_ws, size_t ws_size,
                              hipStream_t stream) {
  float* dout = (float*)d_out;

  static const int exp_sizes[22] = {
    131072, 1, 2048, 1048576, 2048, 2048, 1048576, 1048576, 2048, 2048,
    512, 1, 2048, 1048576, 2048, 2048, 1048576, 1048576, 2048, 2048, 512, 1};
  int code = -1, m = 0;
  if (n_in != 22) { code = 0; m = n_in & 127; }
  else {
    for (int i = 0; i < 22; ++i)
      if (in_sizes[i] != exp_sizes[i]) { code = 1; m = i; break; }
  }
  if (code < 0 && out_size != BB * FUT) { code = 6; m = (out_size >> 8) & 127; }
  if (code < 0 && (d_ws == nullptr || ws_size < NEED_WS)) {
    code = 2; m = (int)(ws_size >> 20); if (m > 127) m = 127;
  }
  if (code >= 0) {
    float v = ldexpf(1.f + (float)m / 128.f, 20 + code);
    beacon_kernel<<<dim3(1), dim3(64), 0, stream>>>(dout, v);
    return;
  }

  const void* x      = d_in[0];
  const void* w_ih0  = d_in[2];
  const void* w_hh0  = d_in[3];
  const void* b_ih0  = d_in[4];
  const void* b_hh0  = d_in[5];
  const void* w_ih1  = d_in[6];
  const void* w_hh1  = d_in[7];
  const void* b_ih1  = d_in[8];
  const void* b_hh1  = d_in[9];
  const void* fc_w   = d_in[10];
  const void* fc_b   = d_in[11];
  const void* pw_ih0 = d_in[12];
  const void* pw_hh0 = d_in[13];
  const void* pb_ih0 = d_in[14];
  const void* pb_hh0 = d_in[15];
  const void* pw_ih1 = d_in[16];
  const void* pw_hh1 = d_in[17];
  const void* pb_ih1 = d_in[18];
  const void* pb_hh1 = d_in[19];
  const void* pfc_w  = d_in[20];
  const void* pfc_b  = d_in[21];

  char* ws = (char*)d_ws;
  Hdr* hdr = (Hdr*)ws;
  int* flg = (int*)(ws + OFF_FLG);
  short* Wc[6];
  for (int i = 0; i < 6; ++i) Wc[i] = (short*)(ws + OFF_W + (size_t)i*WSZ);
  short* H0R = (short*)(ws + OFF_H0);
  short* H1R = (short*)(ws + OFF_H1);
  float* oA  = (float*)(ws + OFF_OA);

  hipMemsetAsync(ws, 0, 20480, stream);         // hdr + counter banks
  hipMemsetAsync(H0R, 0, 4*HSZ + 2*HSZ + OASZ, stream);  // rings + oacc
  probe1_kernel<<<dim3(1), dim3(256), 0, stream>>>(w_hh0, hdr);

  // bf16 copies for LDS staging only (Whh1/pWhh1 streamed from input now)
  dim3 cg(1024), cb(256);
  cvt_kernel<<<cg, cb, 0, stream>>>(w_hh0,  Wc[0], hdr);
  cvt_kernel<<<cg, cb, 0, stream>>>(w_ih1,  Wc[1], hdr);
  cvt_kernel<<<cg, cb, 0, stream>>>(pw_hh0, Wc[3], hdr);
  cvt_kernel<<<cg, cb, 0, stream>>>(pw_ih1, Wc[4], hdr);

  lstm_persist<<<dim3(NBLK), dim3(512), 0, stream>>>(
      x, w_ih0, b_ih0, b_hh0, b_ih1, b_hh1, fc_w, fc_b,
      pw_ih0, pb_ih0, pb_hh0, pb_ih1, pb_hh1, pfc_w, pfc_b,
      Wc[0], Wc[1], Wc[3], Wc[4], w_hh1, pw_hh1,
      H0R, H1R, oA, flg, hdr, dout);
}

// Round 11
// 7217.706 us; speedup vs baseline: 7.9719x; 7.9719x over previous
//
#include <hip/hip_runtime.h>
#include <hip/hip_bf16.h>

// Problem constants (B=256, T=512, H=512, IN=1, future=64)
#define TT  512
#define BB  256
#define HH  512
#define FUT 64
#define NBLK 96            // 32 role0 (U=32) + 64 role1 (U=16)

// Output dtype FP32. Beacons: float 2^(20+code)*(1+m/128):
//  0: n_in!=22  1: in_sizes mismatch @m  2: ws too small  6: out_size wrong
// r23: asymmetric roles on the r18 protocol.
// LAW (r13..r22 measured): all global buffers are uncached at L1/L2 in
// this harness; per-step weight re-reads are fatal (r21: 1.1GB refetch,
// r22: 5GB). Weights must live in LDS. h exchange prices at ~2.06 TB/s
// (IC path). Traffic = #role0*128KB + #role1*256KB per step.
//  - role0: U=32, Whh0/pWhh0 fully in LDS (128KB) -> 16 blocks/bg.
//  - role1: U=16, Wih1+Whh1 both in LDS (2x64KB)  -> 32 blocks/bg.
//    => 20 MB/step (was 24).
//  - role1 prefetches its 16 h1-ring loads BEFORE the pub0 poll (after
//    the pub1 poll): transfer hides under the wait for role0.
// Everything else = r18 verbatim: barrier-free per-step counters,
// h0 ring-4 / h1 ring-2, sc0sc1 h exchange, distributed head partials,
// bounded spins (hang -> passed:false).

struct Hdr { int dtflag; };

typedef __attribute__((ext_vector_type(8))) short short8;
typedef __attribute__((ext_vector_type(4))) float floatx4;

#define OFF_FLG   4096
#define OFF_W     20480
#define WSZ       ((size_t)2048*512*2)          // 2MB bf16 matrix
#define OFF_H0    (OFF_W + 6*WSZ)               // h0 ring: 4 x 256KB
#define HSZ       ((size_t)BB*HH*2)             // 256KB bf16 state
#define OFF_H1    (OFF_H0 + 4*HSZ)              // h1 ring: 2 x 256KB
#define OFF_OA    (OFF_H1 + 2*HSZ)              // o accumulators
#define OASZ      ((size_t)FUT*BB*4)            // 64KB fp32
#define NEED_WS   (OFF_OA + OASZ)               // ~14.2MB

#define SPIN_CAP  (1L << 22)

__device__ __forceinline__ float bf2f(short s) {
  unsigned u = ((unsigned)(unsigned short)s) << 16;
  return __builtin_bit_cast(float, u);
}
__device__ __forceinline__ short f2bf(float f) {
  unsigned u = __builtin_bit_cast(unsigned, f);
  u = u + 0x7FFFu + ((u >> 16) & 1u);
  return (short)(u >> 16);
}
__device__ __forceinline__ float ldf(const void* p, long i, int dt) {
  return dt ? ((const float*)p)[i] : bf2f(((const short*)p)[i]);
}
// 16B coherence-point load/store: dwordx4 with sc0 sc1 (bypass caches,
// IC is the coherence point). Result not ready until manual WAITV.
__device__ __forceinline__ short8 cohld16(const short* p) {
  short8 v;
  asm volatile("global_load_dwordx4 %0, %1, off sc0 sc1"
               : "=v"(v) : "v"(p));
  return v;
}
__device__ __forceinline__ void cohst16(short* p, short8 v) {
  asm volatile("global_store_dwordx4 %0, %1, off sc0 sc1"
               :: "v"(p), "v"(v) : "memory");
}
// counted wait + hard scheduling fence (rule #18: keep MFMA below the wait)
#define WAITV(N) do { asm volatile("s_waitcnt vmcnt(" #N ")" ::: "memory"); \
                      __builtin_amdgcn_sched_barrier(0); } while (0)

__global__ void beacon_kernel(float* dout, float v) {
  if (threadIdx.x == 0) dout[0] = v;
}

__global__ __launch_bounds__(256) void probe1_kernel(const void* w, Hdr* hdr) {
  const int tid = threadIdx.x;
  const short* s = (const short*)w;
  float mx = 0.f;
  #pragma unroll
  for (int i = 0; i < 16; ++i) {
    float v = fabsf(bf2f(s[tid * 16 + i]));
    if (!(v == v)) v = 1e30f;
    mx = fmaxf(mx, v);
  }
  #pragma unroll
  for (int off = 32; off > 0; off >>= 1) mx = fmaxf(mx, __shfl_down(mx, off));
  __shared__ float wmax[4];
  if ((tid & 63) == 0) wmax[tid >> 6] = mx;
  __syncthreads();
  if (tid == 0) {
    float m = fmaxf(fmaxf(wmax[0], wmax[1]), fmaxf(wmax[2], wmax[3]));
    hdr->dtflag = (m > 1000.f) ? 1 : 0;
  }
}

__global__ __launch_bounds__(256) void cvt_kernel(const void* src, short* dst,
                                                  const Hdr* hdr) {
  const int dt = hdr->dtflag;
  const long i = ((long)blockIdx.x * 256 + threadIdx.x);
  if (dt) {
    const float4 v = ((const float4*)src)[i];
    short4 o;
    o.x = f2bf(v.x); o.y = f2bf(v.y); o.z = f2bf(v.z); o.w = f2bf(v.w);
    ((short4*)dst)[i] = o;
  } else {
    ((short4*)dst)[i] = ((const short4*)src)[i];
  }
}

// Persistent 2-layer LSTM, asymmetric layer-split roles, counter pipeline.
__global__ __launch_bounds__(512, 1) void lstm_persist(
    const void* __restrict__ x,
    const void* __restrict__ w_ih0, const void* __restrict__ b_ih0,
    const void* __restrict__ b_hh0, const void* __restrict__ b_ih1,
    const void* __restrict__ b_hh1, const void* __restrict__ fc_w,
    const void* __restrict__ fc_b,  const void* __restrict__ pw_ih0,
    const void* __restrict__ pb_ih0, const void* __restrict__ pb_hh0,
    const void* __restrict__ pb_ih1, const void* __restrict__ pb_hh1,
    const void* __restrict__ pfc_w, const void* __restrict__ pfc_b,
    const short* __restrict__ Whh0, const short* __restrict__ Wih1,
    const short* __restrict__ Whh1, const short* __restrict__ pWhh0,
    const short* __restrict__ pWih1, const short* __restrict__ pWhh1,
    short* H0R, short* H1R, float* oA, int* flg,
    const Hdr* __restrict__ hdr, float* __restrict__ dout)
{
  const int dt  = hdr->dtflag;
  const int tid = threadIdx.x;
  const int bid = blockIdx.x;

  int role, bg, ug, U0;
  if (bid < 32) { role = 0; bg = bid & 1; ug = bid >> 1; U0 = ug * 32; }
  else { role = 1; const int r = bid - 32; bg = r & 1; ug = r >> 1;
         U0 = ug * 16; }
  const int B0 = bg * 128;

  // per-bg counter bank (batch-groups are fully independent)
  int* F     = flg + bg * 2048;
  int* pub0  = F;          // [0..575]  target 16 (role0 blocks/bg)
  int* pub1  = F + 576;    // [0..575]  target 32 (role1 blocks/bg)
  int* cons1 = F + 1152;   // [0..575]  target 32
  int* opub  = F + 1728;   // [0..63]   target 32

  // 128KB weight LDS, role-specific layout:
  //  role0: [kseg(64)][row(128)][8]  (Whh0 slice, 32 units)
  //  role1: [slot(2)][kseg(64)][row(64)][8]  (Wih1 + Whh1, 16 units)
  __shared__ __align__(16) short WlB[65536];
  __shared__ __align__(16) short hbuf[128][32];  // 8KB h repack
  __shared__ float bs[128];                      // bias, idx = u*4+gate
  __shared__ float wih[128];                     // w_ih col (role0)

  const int lane = tid & 63;
  const int wv   = tid >> 6;           // wave 0..7: 16-batch slice each
  const int ln   = lane & 15;          // batch-in-tile AND W-row-in-tile
  const int q    = lane >> 4;          // k-slice / unit-in-quad
  const int bl   = wv*16 + ln;         // batch-in-block 0..127
  const long abase = (long)(B0 + bl) * 512 + q*8;

  float cst[8] = {0.f,0.f,0.f,0.f,0.f,0.f,0.f,0.f};
  float fwk[4] = {0.f,0.f,0.f,0.f};    // head weight col (role1)

// ring slot bases (131072 shorts = one 256KB h state)
#define H0S(G) (H0R + (size_t)((G) & 3) * 131072)
#define H1S(G) (H1R + (size_t)((G) & 1) * 131072)

#define SPIN(COND)                                                           \
  { long guard_ = 0;                                                         \
    while (COND) {                                                           \
      __builtin_amdgcn_s_sleep(1);                                           \
      if (++guard_ > SPIN_CAP) break;                                        \
    } }
#define POLL(P, T)                                                           \
  SPIN(__hip_atomic_load((P), __ATOMIC_RELAXED,                              \
                         __HIP_MEMORY_SCOPE_SYSTEM) < (T))
#define FADD(P)                                                              \
  __hip_atomic_fetch_add((P), 1, __ATOMIC_RELAXED,                           \
                         __HIP_MEMORY_SCOPE_SYSTEM)

// ---- role0 (U=32) machinery ----
#define STAGE32(WG)                                                          \
  for (int i = tid; i < 8192; i += 512) {                                    \
    const int ks_ = i & 63, r_ = i >> 6;                                     \
    const long gr = (long)((r_ & 3)*512 + U0 + (r_ >> 2))*512 + ks_*8;       \
    *(short8*)(WlB + (ks_*128 + r_)*8) = *(const short8*)((WG) + gr);        \
  }
#define BIAS32(B1, B2, WIHP)                                                 \
  if (tid < 128) {                                                           \
    const long j = (long)(tid & 3)*512 + U0 + (tid >> 2);                    \
    bs[tid] = ldf((B1), j, dt) + ldf((B2), j, dt);                           \
    wih[tid] = ldf((const void*)(WIHP), j, dt);                              \
  }
#define ZACC8(A)                                                             \
  _Pragma("unroll") for (int m_ = 0; m_ < 8; ++m_)                           \
    A[m_] = (floatx4){0.f, 0.f, 0.f, 0.f};
#define W0LD(KB, MT) \
  (*(const short8*)(WlB + (((KB)*4 + q)*128 + ((MT)*16 + ln))*8))

// 16 kb, 2 groups of 8, 2-deep counted pipeline
#define GSEG0(AP, ACC)                                                       \
  { const short* ap_ = (AP) + abase;                                         \
    short8 abuf[2][8];                                                       \
    _Pragma("unroll")                                                        \
    for (int i = 0; i < 8; ++i) abuf[0][i] = cohld16(ap_ + i*32);            \
    _Pragma("unroll")                                                        \
    for (int g = 0; g < 2; ++g) {                                            \
      if (g == 0) {                                                          \
        _Pragma("unroll")                                                    \
        for (int i = 0; i < 8; ++i)                                          \
          abuf[1][i] = cohld16(ap_ + (8+i)*32);                              \
        WAITV(8);                                                            \
      } else { WAITV(0); }                                                   \
      _Pragma("unroll")                                                      \
      for (int kk = 0; kk < 8; ++kk) {                                       \
        const int kb = g*8 + kk;                                             \
        _Pragma("unroll")                                                    \
        for (int mt = 0; mt < 8; ++mt)                                       \
          ACC[mt] = __builtin_amdgcn_mfma_f32_16x16x32_bf16(                 \
              W0LD(kb, mt), abuf[g][kk], ACC[mt], 0, 0, 0);                  \
      }                                                                      \
    } }

// role0 epilogue. MODE 0: sv = x[b][TV]; 2: sv = SVO. Ends drained+synced.
#define EPI32(ACC, MODE, TV, SVO, HOUT)                                      \
  { float sv = ((MODE) == 0) ? ldf(x, (long)(B0 + bl)*TT + (TV), dt)         \
                             : (SVO);                                        \
    _Pragma("unroll")                                                        \
    for (int mt = 0; mt < 8; ++mt) {                                         \
      const int u = mt*4 + q;                                                \
      float gi = ACC[mt][0] + bs[u*4+0] + sv*wih[u*4+0];                     \
      float gf = ACC[mt][1] + bs[u*4+1] + sv*wih[u*4+1];                     \
      float gg = ACC[mt][2] + bs[u*4+2] + sv*wih[u*4+2];                     \
      float go = ACC[mt][3] + bs[u*4+3] + sv*wih[u*4+3];                     \
      const float I = 1.f/(1.f+expf(-gi));                                   \
      const float F = 1.f/(1.f+expf(-gf));                                   \
      const float G = tanhf(gg);                                             \
      const float O = 1.f/(1.f+expf(-go));                                   \
      const float cn = F*cst[mt] + I*G;                                      \
      cst[mt] = cn;                                                          \
      hbuf[bl][u] = f2bf(O * tanhf(cn));                                     \
    }                                                                        \
    __syncthreads();                                                         \
    { const int b_ = tid >> 2, hf_ = tid & 3;                                \
      cohst16((HOUT) + (long)(B0 + b_)*512 + U0 + hf_*8,                     \
              *(const short8*)&hbuf[b_][hf_*8]); }                           \
    asm volatile("s_waitcnt vmcnt(0)" ::: "memory");                         \
    __syncthreads(); }

// ---- role1 (U=16) machinery ----
#define STAGE16(SLOT, WG)                                                    \
  for (int i = tid; i < 4096; i += 512) {                                    \
    const int ks_ = i & 63, r_ = i >> 6;                                     \
    const long gr = (long)((r_ & 3)*512 + U0 + (r_ >> 2))*512 + ks_*8;       \
    *(short8*)(WlB + (((SLOT)*64 + ks_)*64 + r_)*8) =                        \
        *(const short8*)((WG) + gr);                                         \
  }
#define BIAS16(B1, B2)                                                       \
  if (tid < 64) {                                                            \
    const long j = (long)(tid & 3)*512 + U0 + (tid >> 2);                    \
    bs[tid] = ldf((B1), j, dt) + ldf((B2), j, dt);                           \
  }
#define FWLOAD(FWP)                                                          \
  { _Pragma("unroll")                                                        \
    for (int mt = 0; mt < 4; ++mt)                                           \
      fwk[mt] = ldf((FWP), U0 + mt*4 + q, dt); }
#define ZACC4(A)                                                             \
  _Pragma("unroll") for (int m_ = 0; m_ < 4; ++m_)                           \
    A[m_] = (floatx4){0.f, 0.f, 0.f, 0.f};
#define W1LD(S, KB, MT) \
  (*(const short8*)(WlB + (((S)*64 + ((KB)*4 + q))*64 + ((MT)*16 + ln))*8))

// issue all 16 h1-ring loads (hidden under the pub0 poll's barrier drain)
#define PREFH1(AP1)                                                          \
  { const short* p1_ = (AP1) + abase;                                        \
    _Pragma("unroll")                                                        \
    for (int i = 0; i < 16; ++i) h1r[i] = cohld16(p1_ + i*32); }

// pass1: h0 x Wih1(LDS), 4 groups of 4, 1-deep; pass2: h1r x Whh1(LDS)
#define GSEGR1(AP0, ACC)                                                     \
  { const short* p0_ = (AP0) + abase;                                        \
    short8 abuf[2][4];                                                       \
    _Pragma("unroll")                                                        \
    for (int i = 0; i < 4; ++i) abuf[0][i] = cohld16(p0_ + i*32);            \
    _Pragma("unroll")                                                        \
    for (int g = 0; g < 4; ++g) {                                            \
      if (g < 3) {                                                           \
        _Pragma("unroll")                                                    \
        for (int i = 0; i < 4; ++i)                                          \
          abuf[(g+1)&1][i] = cohld16(p0_ + ((g+1)*4 + i)*32);                \
        WAITV(4);                                                            \
      } else { WAITV(0); }                                                   \
      _Pragma("unroll")                                                      \
      for (int kk = 0; kk < 4; ++kk) {                                       \
        const int kb = g*4 + kk;                                             \
        _Pragma("unroll")                                                    \
        for (int mt = 0; mt < 4; ++mt)                                       \
          ACC[mt] = __builtin_amdgcn_mfma_f32_16x16x32_bf16(                 \
              W1LD(0, kb, mt), abuf[g&1][kk], ACC[mt], 0, 0, 0);             \
      }                                                                      \
    }                                                                        \
    _Pragma("unroll")                                                        \
    for (int kb = 0; kb < 16; ++kb) {                                        \
      _Pragma("unroll")                                                      \
      for (int mt = 0; mt < 4; ++mt)                                         \
        ACC[mt] = __builtin_amdgcn_mfma_f32_16x16x32_bf16(                   \
            W1LD(1, kb, mt), h1r[kb], ACC[mt], 0, 0, 0);                     \
    } }

// role1 epilogue (no input term). OSLOT != 0: head partial atomicAdd.
#define EPI16(ACC, HOUT, OSLOT)                                              \
  { float po = 0.f;                                                          \
    _Pragma("unroll")                                                        \
    for (int mt = 0; mt < 4; ++mt) {                                         \
      const int u = mt*4 + q;                                                \
      float gi = ACC[mt][0] + bs[u*4+0];                                     \
      float gf = ACC[mt][1] + bs[u*4+1];                                     \
      float gg = ACC[mt][2] + bs[u*4+2];                                     \
      float go = ACC[mt][3] + bs[u*4+3];                                     \
      const float I = 1.f/(1.f+expf(-gi));                                   \
      const float F = 1.f/(1.f+expf(-gf));                                   \
      const float G = tanhf(gg);                                             \
      const float O = 1.f/(1.f+expf(-go));                                   \
      const float cn = F*cst[mt] + I*G;                                      \
      cst[mt] = cn;                                                          \
      const float hv = O * tanhf(cn);                                        \
      hbuf[bl][u] = f2bf(hv);                                                \
      if ((OSLOT) != (float*)0) po += fwk[mt] * hv;                          \
    }                                                                        \
    if ((OSLOT) != (float*)0) {                                              \
      po += __shfl_xor(po, 16); po += __shfl_xor(po, 32);                    \
      if (lane < 16) atomicAdd((float*)(OSLOT) + bl, po);                    \
    }                                                                        \
    __syncthreads();                                                         \
    if (tid < 256) {                                                         \
      const int b_ = tid >> 1, hf_ = tid & 1;                                \
      cohst16((HOUT) + (long)(B0 + b_)*512 + U0 + hf_*8,                     \
              *(const short8*)&hbuf[b_][hf_*8]);                             \
    }                                                                        \
    asm volatile("s_waitcnt vmcnt(0)" ::: "memory");                         \
    __syncthreads(); }

  const float fcb  = ldf(fc_b, 0, dt);
  const float pfcb = ldf(pfc_b, 0, dt);

  if (role == 0) {
    // ======== role0: L0 chain (U=32), Whh0 in LDS, runs ahead ========
    STAGE32(Whh0);
    BIAS32(b_ih0, b_hh0, w_ih0);
    __syncthreads();
    for (int g = 0; g < TT; ++g) {
      if (tid == 0) {
        if (g > 0)  POLL(pub0 + g - 1, 16);     // peers published h0(g-1)
        if (g >= 4) POLL(cons1 + g - 4, 32);    // ring-4 backpressure
      }
      __syncthreads();
      floatx4 a[8]; ZACC8(a);
      GSEG0(H0S(g-1), a);
      EPI32(a, 0, g, 0.f, H0S(g));
      if (tid == 0) FADD(pub0 + g);
    }
    STAGE32(pWhh0);
    BIAS32(pb_ih0, pb_hh0, pw_ih0);
    __syncthreads();
    for (int s = 1; s < FUT; ++s) {
      const int g = 511 + s;
      if (tid == 0) {
        POLL(pub0 + g - 1, 16);
        POLL(cons1 + g - 4, 32);
        POLL(opub + s - 1, 32);
      }
      __syncthreads();
      const float ob_ = (s == 1) ? fcb : pfcb;
      const float o_ = __hip_atomic_load(
          oA + (long)(s-1)*BB + B0 + bl,
          __ATOMIC_RELAXED, __HIP_MEMORY_SCOPE_SYSTEM) + ob_;
      if (ug == 0 && lane < 16)
        dout[(long)(B0 + bl)*FUT + (s-1)] = o_;
      floatx4 a[8]; ZACC8(a);
      GSEG0(H0S(g-1), a);
      EPI32(a, 2, 0, o_, H0S(g));
      if (tid == 0) FADD(pub0 + g);
    }
    if (tid == 0) POLL(opub + FUT - 1, 32);
    __syncthreads();
    if (ug == 0 && lane < 16) {
      const float o_ = __hip_atomic_load(
          oA + (long)(FUT-1)*BB + B0 + bl,
          __ATOMIC_RELAXED, __HIP_MEMORY_SCOPE_SYSTEM) + pfcb;
      dout[(long)(B0 + bl)*FUT + (FUT-1)] = o_;
    }
  } else {
    // ======== role1: L1 chain (U=16), Wih1+Whh1 in LDS ========
    short8 h1r[16];
    STAGE16(0, Wih1); STAGE16(1, Whh1);
    BIAS16(b_ih1, b_hh1);
    FWLOAD(fc_w);
    __syncthreads();
    for (int g = 0; g < TT; ++g) {
      if (tid == 0 && g > 0) POLL(pub1 + g - 1, 32);   // peers' h1(g-1)
      __syncthreads();
      PREFH1(H1S(g-1));                 // in flight; drains at next barrier
      if (tid == 0) POLL(pub0 + g, 16);                // h0(g) ready
      __syncthreads();
      floatx4 a[4]; ZACC4(a);
      GSEGR1(H0S(g), a);
      __syncthreads();                  // all waves done reading h0(g)
      if (tid == 0) FADD(cons1 + g);
      float* os_ = (g == TT-1) ? (oA + B0) : (float*)0;
      EPI16(a, H1S(g), os_);
      if (tid == 0) {
        FADD(pub1 + g);
        if (g == TT-1) FADD(opub + 0);
      }
    }
    STAGE16(0, pWih1); STAGE16(1, pWhh1);
    BIAS16(pb_ih1, pb_hh1);
    FWLOAD(pfc_w);
    __syncthreads();
    for (int s = 1; s < FUT; ++s) {
      const int g = 511 + s;
      if (tid == 0) POLL(pub1 + g - 1, 32);
      __syncthreads();
      PREFH1(H1S(g-1));
      if (tid == 0) POLL(pub0 + g, 16);
      __syncthreads();
      floatx4 a[4]; ZACC4(a);
      GSEGR1(H0S(g), a);
      __syncthreads();
      if (tid == 0) FADD(cons1 + g);
      EPI16(a, H1S(g), oA + (long)s*BB + B0);
      if (tid == 0) { FADD(pub1 + g); FADD(opub + s); }
    }
  }
#undef STAGE32
#undef BIAS32
#undef ZACC8
#undef W0LD
#undef GSEG0
#undef EPI32
#undef STAGE16
#undef BIAS16
#undef FWLOAD
#undef ZACC4
#undef W1LD
#undef PREFH1
#undef GSEGR1
#undef EPI16
#undef SPIN
#undef POLL
#undef FADD
#undef H0S
#undef H1S
}

extern "C" void kernel_launch(void* const* d_in, const int* in_sizes, int n_in,
                              void* d_out, int out_size, void* d_ws, size_t ws_size,
                              hipStream_t stream) {
  float* dout = (float*)d_out;

  static const int exp_sizes[22] = {
    131072, 1, 2048, 1048576, 2048, 2048, 1048576, 1048576, 2048, 2048,
    512, 1, 2048, 1048576, 2048, 2048, 1048576, 1048576, 2048, 2048, 512, 1};
  int code = -1, m = 0;
  if (n_in != 22) { code = 0; m = n_in & 127; }
  else {
    for (int i = 0; i < 22; ++i)
      if (in_sizes[i] != exp_sizes[i]) { code = 1; m = i; break; }
  }
  if (code < 0 && out_size != BB * FUT) { code = 6; m = (out_size >> 8) & 127; }
  if (code < 0 && (d_ws == nullptr || ws_size < NEED_WS)) {
    code = 2; m = (int)(ws_size >> 20); if (m > 127) m = 127;
  }
  if (code >= 0) {
    float v = ldexpf(1.f + (float)m / 128.f, 20 + code);
    beacon_kernel<<<dim3(1), dim3(64), 0, stream>>>(dout, v);
    return;
  }

  const void* x      = d_in[0];
  const void* w_ih0  = d_in[2];
  const void* w_hh0  = d_in[3];
  const void* b_ih0  = d_in[4];
  const void* b_hh0  = d_in[5];
  const void* w_ih1  = d_in[6];
  const void* w_hh1  = d_in[7];
  const void* b_ih1  = d_in[8];
  const void* b_hh1  = d_in[9];
  const void* fc_w   = d_in[10];
  const void* fc_b   = d_in[11];
  const void* pw_ih0 = d_in[12];
  const void* pw_hh0 = d_in[13];
  const void* pb_ih0 = d_in[14];
  const void* pb_hh0 = d_in[15];
  const void* pw_ih1 = d_in[16];
  const void* pw_hh1 = d_in[17];
  const void* pb_ih1 = d_in[18];
  const void* pb_hh1 = d_in[19];
  const void* pfc_w  = d_in[20];
  const void* pfc_b  = d_in[21];

  char* ws = (char*)d_ws;
  Hdr* hdr = (Hdr*)ws;
  int* flg = (int*)(ws + OFF_FLG);
  short* Wc[6];
  for (int i = 0; i < 6; ++i) Wc[i] = (short*)(ws + OFF_W + (size_t)i*WSZ);
  short* H0R = (short*)(ws + OFF_H0);
  short* H1R = (short*)(ws + OFF_H1);
  float* oA  = (float*)(ws + OFF_OA);

  hipMemsetAsync(ws, 0, 20480, stream);         // hdr + counter banks
  hipMemsetAsync(H0R, 0, 4*HSZ + 2*HSZ + OASZ, stream);  // rings + oacc
  probe1_kernel<<<dim3(1), dim3(256), 0, stream>>>(w_hh0, hdr);

  dim3 cg(1024), cb(256);
  cvt_kernel<<<cg, cb, 0, stream>>>(w_hh0,  Wc[0], hdr);
  cvt_kernel<<<cg, cb, 0, stream>>>(w_ih1,  Wc[1], hdr);
  cvt_kernel<<<cg, cb, 0, stream>>>(w_hh1,  Wc[2], hdr);
  cvt_kernel<<<cg, cb, 0, stream>>>(pw_hh0, Wc[3], hdr);
  cvt_kernel<<<cg, cb, 0, stream>>>(pw_ih1, Wc[4], hdr);
  cvt_kernel<<<cg, cb, 0, stream>>>(pw_hh1, Wc[5], hdr);

  lstm_persist<<<dim3(NBLK), dim3(512), 0, stream>>>(
      x, w_ih0, b_ih0, b_hh0, b_ih1, b_hh1, fc_w, fc_b,
      pw_ih0, pb_ih0, pb_hh0, pb_ih1, pb_hh1, pfc_w, pfc_b,
      Wc[0], Wc[1], Wc[2], Wc[3], Wc[4], Wc[5],
      H0R, H1R, oA, flg, hdr, dout);
}